// Round 1
// baseline (522.230 us; speedup 1.0000x reference)
//
#include <hip/hip_runtime.h>

#define N_PTS  64
#define N_FINE 64
#define EPS    1e-5f
#define WAVES_PER_BLOCK 4

// One 64-lane wave per ray. Lane i holds z[i] and w[i].
__global__ __launch_bounds__(256) void ray_refine_kernel(
    const float* __restrict__ lengths,      // [n_rays, 64]
    const float* __restrict__ ray_weights,  // [n_rays, 64]
    float* __restrict__ out,                // [n_rays, 128]
    int n_rays)
{
    const int lane = threadIdx.x & 63;
    const int wid  = threadIdx.x >> 6;
    int ray = blockIdx.x * WAVES_PER_BLOCK + wid;
    // clamp (never taken for divisible grids; avoids divergent syncthreads)
    if (ray >= n_rays) ray = n_rays - 1;

    __shared__ float s_cdf[WAVES_PER_BLOCK][64];
    __shared__ float s_mid[WAVES_PER_BLOCK][64];
    __shared__ float s_a[WAVES_PER_BLOCK][64];
    __shared__ float s_b[WAVES_PER_BLOCK][64];
    __shared__ float s_out[WAVES_PER_BLOCK][128];

    const size_t base = (size_t)ray * 64;
    const float z  = lengths[base + lane];
    const float wf = ray_weights[base + lane];

    // mids[i] = 0.5*(z[i]+z[i+1]), i in [0,63)
    const float zn  = __shfl_down(z, 1);
    const float mid = 0.5f * (z + zn);

    // weights used by the pdf: ray_weights[1..62]  ->  w[i] = wf[i+1] + eps, i in [0,62)
    const float wnext = __shfl_down(wf, 1);
    float w = (lane < 62) ? (wnext + EPS) : 0.0f;

    // inclusive prefix sum across the wave
    float c = w;
    #pragma unroll
    for (int off = 1; off < 64; off <<= 1) {
        float y = __shfl_up(c, off);
        if (lane >= off) c += y;
    }
    const float total = __shfl(c, 63);
    const float inv_total = 1.0f / total;

    float* cdf  = s_cdf[wid];
    float* mids = s_mid[wid];
    // cdf has 63 entries: cdf[0]=0, cdf[k]=cumsum(pdf)[k-1]
    if (lane < 62) cdf[lane + 1] = c * inv_total;
    if (lane == 63) cdf[0] = 0.0f;
    if (lane < 63) mids[lane] = mid;
    __syncthreads();

    // u = linspace(0,1,64); endpoint exact like np.linspace
    const float u = (lane == 63) ? 1.0f : (float)lane * (1.0f / 63.0f);

    // ind = searchsorted(cdf[0..62], u, side='right')  (upper bound, in [0,63])
    int ind = 0;
    #pragma unroll
    for (int step = 32; step > 0; step >>= 1) {
        int nxt = ind + step;
        if (nxt <= 63 && cdf[nxt - 1] <= u) ind = nxt;
    }
    const int below = (ind - 1 > 0) ? (ind - 1) : 0;
    const int above = (ind < 62) ? ind : 62;
    const float cb = cdf[below];
    const float ca = cdf[above];
    const float bb = mids[below];
    const float ba = mids[above];
    float denom = ca - cb;
    if (denom < EPS) denom = 1.0f;
    const float t = (u - cb) / denom;
    const float sample = bb + t * (ba - bb);

    float* A = s_a[wid];   // sorted z (strictly increasing)
    float* B = s_b[wid];   // sorted samples (non-decreasing)
    A[lane] = z;
    B[lane] = sample;
    __syncthreads();

    // merge ranks: posA = lane + #{B < z}; posB = lane + #{A <= sample}
    int cntB = 0;
    #pragma unroll
    for (int step = 64; step > 0; step >>= 1) {
        int nxt = cntB + step;
        if (nxt <= 64 && B[nxt - 1] < z) cntB = nxt;
    }
    int cntA = 0;
    #pragma unroll
    for (int step = 64; step > 0; step >>= 1) {
        int nxt = cntA + step;
        if (nxt <= 64 && A[nxt - 1] <= sample) cntA = nxt;
    }

    float* O = s_out[wid];
    O[lane + cntB] = z;
    O[lane + cntA] = sample;
    __syncthreads();

    // coalesced write: 128 floats per ray, float2 per lane
    float2 v;
    v.x = O[2 * lane];
    v.y = O[2 * lane + 1];
    ((float2*)(out + (size_t)ray * 128))[lane] = v;
}

extern "C" void kernel_launch(void* const* d_in, const int* in_sizes, int n_in,
                              void* d_out, int out_size, void* d_ws, size_t ws_size,
                              hipStream_t stream) {
    // inputs (setup_inputs order): origins, directions, lengths, xys, ray_weights
    const float* lengths     = (const float*)d_in[2];
    const float* ray_weights = (const float*)d_in[4];
    float* out = (float*)d_out;

    const int n_rays = in_sizes[2] / N_PTS;
    const int grid = (n_rays + WAVES_PER_BLOCK - 1) / WAVES_PER_BLOCK;
    ray_refine_kernel<<<grid, 256, 0, stream>>>(lengths, ray_weights, out, n_rays);
}

// Round 2
// 474.451 us; speedup vs baseline: 1.1007x; 1.1007x over previous
//
#include <hip/hip_runtime.h>

#define EPS 1e-5f
#define WPB 4  // waves (rays) per 256-thread block

// DPP move with 0-fill (bound_ctrl): returns src shifted per CTRL, 0 where invalid.
template<int CTRL>
__device__ __forceinline__ float dppf(float v) {
    return __int_as_float(__builtin_amdgcn_update_dpp(
        0, __float_as_int(v), CTRL, 0xf, 0xf, true));
}
template<int CTRL>
__device__ __forceinline__ int dppi(int v) {
    return __builtin_amdgcn_update_dpp(0, v, CTRL, 0xf, 0xf, true);
}

__device__ __forceinline__ float readlane_f(float v, int l) {
    return __int_as_float(__builtin_amdgcn_readlane(__float_as_int(v), l));
}

// wave-private LDS ordering fence (all sharing is intra-wave; no s_barrier needed)
__device__ __forceinline__ void lds_fence() {
    asm volatile("s_waitcnt lgkmcnt(0)" ::: "memory");
}

// inclusive sum-scan across 64 lanes: 4 DPP row steps + cross-row via readlane
__device__ __forceinline__ float wave_scan_sum(float x, int lane) {
    x += dppf<0x111>(x);   // row_shr:1
    x += dppf<0x112>(x);   // row_shr:2
    x += dppf<0x114>(x);   // row_shr:4
    x += dppf<0x118>(x);   // row_shr:8  -> inclusive within each 16-lane row
    float r0 = readlane_f(x, 15);
    float r1 = readlane_f(x, 31);
    float r2 = readlane_f(x, 47);
    int row = lane >> 4;
    float off = 0.0f;
    if (row == 1) off = r0;
    else if (row == 2) off = r0 + r1;
    else if (row == 3) off = (r0 + r1) + r2;
    return x + off;
}

// inclusive max-scan across 64 lanes (values >= 0)
__device__ __forceinline__ int wave_scan_max(int x, int lane) {
    x = max(x, dppi<0x111>(x));
    x = max(x, dppi<0x112>(x));
    x = max(x, dppi<0x114>(x));
    x = max(x, dppi<0x118>(x));
    int r0 = __builtin_amdgcn_readlane(x, 15);
    int r1 = __builtin_amdgcn_readlane(x, 31);
    int r2 = __builtin_amdgcn_readlane(x, 47);
    int row = lane >> 4;
    int off = 0;
    if (row == 1) off = r0;
    else if (row == 2) off = max(r0, r1);
    else if (row == 3) off = max(max(r0, r1), r2);
    return max(x, off);
}

__device__ __forceinline__ float uval(int j) {
    return (j >= 63) ? 1.0f : (float)j * (1.0f / 63.0f);
}

// One 64-lane wave per ray; lane i holds z[i], w[i]. No __syncthreads anywhere.
__global__ __launch_bounds__(256) void ray_refine_kernel(
    const float* __restrict__ lengths,      // [n_rays, 64]
    const float* __restrict__ ray_weights,  // [n_rays, 64]
    float* __restrict__ out,                // [n_rays, 128]
    int n_rays)
{
    const int lane = threadIdx.x & 63;
    const int wid  = threadIdx.x >> 6;
    int ray = blockIdx.x * WPB + wid;
    if (ray >= n_rays) ray = n_rays - 1;

    __shared__ float sZ[WPB][64];      // z values
    __shared__ float sC[WPB][64];      // cdf values (entries 0..62 valid)
    __shared__ int   sS[WPB][64][2];   // [.][0]=ind scatter slots, [.][1]=rank slots

    const size_t base = (size_t)ray * 64;
    const float z  = lengths[base + lane];
    const float wf = ray_weights[base + lane];

    // cdf_k = (sum_{i<k} w_i)/total where w_i = ray_weights[i+1]+eps, i in [0,62).
    // Map: lane k's scan input = w_{k-1} = wf[k]+eps for k in [1,62]; 0 otherwise.
    // Then inclusive-scan(lane k) = total*cdf_k, and scan(lane 62) = total.
    float win = (lane >= 1 && lane <= 62) ? (wf + EPS) : 0.0f;
    float x = wave_scan_sum(win, lane);
    const float total = readlane_f(x, 62);
    const float inv_total = 1.0f / total;
    const float cv = x * inv_total;    // cdf value at this lane (valid for lane<63)

    sZ[wid][lane] = z;
    sC[wid][lane] = cv;
    sS[wid][lane][0] = 0;
    sS[wid][lane][1] = 0;
    lds_fence();

    // --- inverse-CDF sample index via scatter + max-scan ---
    // m_k = smallest j with cdf_k <= u_j (exact: arithmetic guess + comparison fixup)
    int m = (int)ceilf(cv * 63.0f);
    m = min(max(m, 0), 64);
    if (m > 0 && cv <= uval(m - 1)) m--;
    if (m > 0 && cv <= uval(m - 1)) m--;
    if (m < 64 && cv > uval(m)) m++;
    if (m < 64 && cv > uval(m)) m++;
    if (lane < 63 && m < 64) atomicMax(&sS[wid][m][0], lane + 1);
    lds_fence();

    // ind_j = #{k: m_k <= j} = max-scan of scattered (k+1)   (m_k non-decreasing)
    const int ind = wave_scan_max(sS[wid][lane][0], lane);    // in [1,63]
    const int below = ind - 1;                                 // in [0,62]
    const int above = min(ind, 62);

    const float cb  = sC[wid][below];
    const float ca  = sC[wid][above];
    const float zb  = sZ[wid][below];
    const float zb1 = sZ[wid][below + 1];
    const float za  = sZ[wid][above];
    const float za1 = sZ[wid][above + 1];
    const float bb = 0.5f * (zb + zb1);    // mids[below]
    const float ba = 0.5f * (za + za1);    // mids[above]
    float denom = ca - cb;
    if (denom < EPS) denom = 1.0f;
    const float u = uval(lane);
    const float t = (u - cb) / denom;
    const float s = bb + t * (ba - bb);    // fine sample, in (z[below], z[above+1])

    // rank of sample among z: structurally r in {below+1, below+2}
    const int r = below + 1 + ((above > below && zb1 <= s) ? 1 : 0);   // in [1,63]

    // rank of z among samples: cntB_i = #{j: r_j <= i} via scatter + max-scan
    atomicMax(&sS[wid][r][1], lane + 1);
    lds_fence();
    const int cntB = wave_scan_max(sS[wid][lane][1], lane);

    // merged positions (valid permutation: z-before-sample tie-break both ways)
    const size_t ob = (size_t)ray * 128;
    out[ob + lane + cntB] = z;   // pos = i + #{samples < z_i}
    out[ob + lane + r]    = s;   // pos = j + #{z <= sample_j}
}

extern "C" void kernel_launch(void* const* d_in, const int* in_sizes, int n_in,
                              void* d_out, int out_size, void* d_ws, size_t ws_size,
                              hipStream_t stream) {
    // inputs (setup_inputs order): origins, directions, lengths, xys, ray_weights
    const float* lengths     = (const float*)d_in[2];
    const float* ray_weights = (const float*)d_in[4];
    float* out = (float*)d_out;

    const int n_rays = in_sizes[2] / 64;
    const int grid = (n_rays + WPB - 1) / WPB;
    ray_refine_kernel<<<grid, 256, 0, stream>>>(lengths, ray_weights, out, n_rays);
}